// Round 4
// baseline (285.695 us; speedup 1.0000x reference)
//
#include <hip/hip_runtime.h>
#include <hip/hip_bf16.h>
#include <cstdint>

#define EPS2f 1e-5f

typedef __bf16 bf16x8 __attribute__((ext_vector_type(8)));
typedef float floatx4 __attribute__((ext_vector_type(4)));
typedef _Float16 half8 __attribute__((ext_vector_type(8)));
typedef __fp16 fp16x2 __attribute__((ext_vector_type(2)));

static constexpr int Bn = 4, Cn = 256, Nn = 4096;

// workspace layout (float offsets) — total 37,818,880 floats = 151.28 MB
// (round-3 proved ws_size >= 151.59 MB, so no fallback path needed)
static constexpr size_t MSE1P = 0;        // 192
static constexpr size_t MSE2P = 256;      // 1024
static constexpr size_t CSP   = 1536;     // 1024
static constexpr size_t MEANX = 2560;     // 1024
static constexpr size_t MEANY = 3584;     // 1024
static constexpr size_t IXN   = 4608;     // 16384
static constexpr size_t IYN   = 20992;    // 16384
static constexpr size_t DMIN  = 37376;    // 16384
static constexpr size_t RSUM  = 53760;    // 16384 (contiguous after DMIN)
static constexpr size_t XCO   = 70144;    // bf16[4*4096*256] = 2097152 floats
static constexpr size_t YCO   = 70144 + 2097152;
static constexpr size_t SOFF  = 70144 + 2 * 2097152;  // fp16[4*4096*4096] = 33554432 floats

__device__ __forceinline__ unsigned short f2bf(float f) {
    unsigned u = __float_as_uint(f);
    u += 0x7fffu + ((u >> 16) & 1u);
    return (unsigned short)(u >> 16);
}

// -------- prep1: channel means + both MSE partials + dmin/rsum init --------
// grid: 1024 (feature channels) + 192 (mse1) + 128 (init) = 1344 blocks
__global__ __launch_bounds__(256) void prep1(const float4* __restrict__ outs,
                                             const float4* __restrict__ tgts,
                                             const float4* __restrict__ of4,
                                             const float4* __restrict__ tf4,
                                             float* __restrict__ ws) {
    const int bid = blockIdx.x, t = threadIdx.x;
    __shared__ float red[12];
    if (bid < 1024) {
        const int c = bid & 255, b = bid >> 8;
        const float4* po = of4 + ((size_t)b * Cn + c) * (Nn / 4);
        const float4* pt = tf4 + ((size_t)b * Cn + c) * (Nn / 4);
        float so = 0.f, st = 0.f, sq = 0.f;
        for (int i = t; i < 1024; i += 256) {
            float4 o = po[i], q = pt[i];
            so += o.x + o.y + o.z + o.w;
            st += q.x + q.y + q.z + q.w;
            float dx = o.x - q.x, dy = o.y - q.y, dz = o.z - q.z, dw = o.w - q.w;
            sq += dx * dx + dy * dy + dz * dz + dw * dw;
        }
        for (int m = 1; m < 64; m <<= 1) {
            so += __shfl_xor(so, m); st += __shfl_xor(st, m); sq += __shfl_xor(sq, m);
        }
        if ((t & 63) == 0) { int w = t >> 6; red[w * 3] = so; red[w * 3 + 1] = st; red[w * 3 + 2] = sq; }
        __syncthreads();
        if (t == 0) {
            so = red[0] + red[3] + red[6] + red[9];
            st = red[1] + red[4] + red[7] + red[10];
            sq = red[2] + red[5] + red[8] + red[11];
            ws[MEANX + b * Cn + c] = so * (1.f / 4096.f);
            ws[MEANY + b * Cn + c] = st * (1.f / 4096.f);
            ws[MSE2P + bid] = sq;
        }
    } else if (bid < 1216) {
        const int base = bid - 1024;  // 0..191
        float sq = 0.f;
        for (int i = base * 256 + t; i < 196608; i += 192 * 256) {
            float4 a = outs[i], b4 = tgts[i];
            float dx = a.x - b4.x, dy = a.y - b4.y, dz = a.z - b4.z, dw = a.w - b4.w;
            sq += dx * dx + dy * dy + dz * dz + dw * dw;
        }
        for (int m = 1; m < 64; m <<= 1) sq += __shfl_xor(sq, m);
        if ((t & 63) == 0) red[t >> 6] = sq;
        __syncthreads();
        if (t == 0) ws[MSE1P + base] = red[0] + red[1] + red[2] + red[3];
    } else {
        const int i = (bid - 1216) * 256 + t;  // 0..32767 → dmin then rsum
        ws[DMIN + i] = (i < 16384) ? __builtin_inff() : 0.f;
    }
}

// -------- center: per-channel centering, bf16 [b][n][c] transpose, inv norms ----
__global__ __launch_bounds__(256) void center_fused(const float* __restrict__ ofeat,
                                                    const float* __restrict__ tfeat,
                                                    float* __restrict__ ws) {
    const int b = blockIdx.y, nb = blockIdx.x, z = blockIdx.z;
    const float* feat = z ? tfeat : ofeat;
    const float* mean = ws + (z ? MEANY : MEANX);
    unsigned short* outb = (unsigned short*)(ws + (z ? YCO : XCO));
    float* inv = ws + (z ? IYN : IXN);
    __shared__ float mean_s[256];
    __shared__ float sq_s[256];
    const int t = threadIdx.x;
    mean_s[t] = mean[b * Cn + t];
    __syncthreads();
    const int pos = t & 63, cg = t >> 6;
    const int n = nb * 64 + pos;
    const float* fb = feat + (size_t)b * Cn * Nn;
    unsigned short* ob = outb + ((size_t)b * Nn + n) * Cn;
    float ss = 0.f;
    for (int c0 = cg * 64; c0 < cg * 64 + 64; c0 += 8) {
        unsigned short tmp[8];
        #pragma unroll
        for (int u = 0; u < 8; ++u) {
            float v = fb[(size_t)(c0 + u) * Nn + n] - mean_s[c0 + u];
            ss += v * v;
            tmp[u] = f2bf(v);
        }
        uint4 pk;
        pk.x = (unsigned)tmp[0] | ((unsigned)tmp[1] << 16);
        pk.y = (unsigned)tmp[2] | ((unsigned)tmp[3] << 16);
        pk.z = (unsigned)tmp[4] | ((unsigned)tmp[5] << 16);
        pk.w = (unsigned)tmp[6] | ((unsigned)tmp[7] << 16);
        *(uint4*)(ob + c0) = pk;
    }
    sq_s[t] = ss;
    __syncthreads();
    if (t < 64) {
        float s = sq_s[t] + sq_s[t + 64] + sq_s[t + 128] + sq_s[t + 192];
        inv[(size_t)b * Nn + nb * 64 + t] = 1.f / sqrtf(s);
    }
}

// -------- register-direct GEMM: frags straight from L2, no staging barriers ----
__global__ __launch_bounds__(256) void gemm_store(const unsigned short* __restrict__ Xc,
                                                  const unsigned short* __restrict__ Yc,
                                                  const float* __restrict__ ixn,
                                                  const float* __restrict__ iyn,
                                                  float* __restrict__ dmin,
                                                  _Float16* __restrict__ S) {
    __shared__ __align__(16) unsigned short T[128 * 128];  // 32 KB fp16 tile
    __shared__ float ixn_s[128], iyn_s[128];

    const int t = threadIdx.x;
    const int bx = blockIdx.x, by = blockIdx.y, b = blockIdx.z;
    const size_t nb = (size_t)b * Nn;

    if (t < 128) ixn_s[t] = ixn[nb + bx * 128 + t];
    else iyn_s[t - 128] = iyn[nb + by * 128 + (t - 128)];
    __syncthreads();

    const int wid = t >> 6, lane = t & 63;
    const int wm = wid >> 1, wn = wid & 1;
    const int lr = lane & 15, lq = lane >> 4;

    // lane's fragment base: A row (x) = bx*128 + wm*64 + i*16 + lr, k = ks*32 + lq*8
    const unsigned short* Abase = Xc + (nb + bx * 128 + wm * 64 + lr) * Cn + lq * 8;
    const unsigned short* Bbase = Yc + (nb + by * 128 + wn * 64 + lr) * Cn + lq * 8;

    floatx4 acc[4][4];
    #pragma unroll
    for (int i = 0; i < 4; i++)
        #pragma unroll
        for (int j = 0; j < 4; j++) acc[i][j] = (floatx4){0.f, 0.f, 0.f, 0.f};

    bf16x8 af[2][4], bv[2][4];
    #pragma unroll
    for (int i = 0; i < 4; i++) {
        af[0][i] = *(const bf16x8*)(Abase + i * 16 * Cn);
        bv[0][i] = *(const bf16x8*)(Bbase + i * 16 * Cn);
    }
    #pragma unroll
    for (int ks = 0; ks < 8; ks++) {
        const int cur = ks & 1, nxt = cur ^ 1;
        if (ks < 7) {
            #pragma unroll
            for (int i = 0; i < 4; i++) {
                af[nxt][i] = *(const bf16x8*)(Abase + i * 16 * Cn + (ks + 1) * 32);
                bv[nxt][i] = *(const bf16x8*)(Bbase + i * 16 * Cn + (ks + 1) * 32);
            }
        }
        #pragma unroll
        for (int i = 0; i < 4; i++)
            #pragma unroll
            for (int j = 0; j < 4; j++)
                acc[i][j] = __builtin_amdgcn_mfma_f32_16x16x32_bf16(af[cur][i], bv[cur][j], acc[i][j], 0, 0, 0);
    }

    // epilogue: cos → rmin (dmin) + fp16 tile in LDS
    float rmin[16];
    #pragma unroll
    for (int k = 0; k < 16; k++) rmin[k] = __builtin_inff();
    float ix[16];
    #pragma unroll
    for (int i = 0; i < 4; i++)
        #pragma unroll
        for (int r = 0; r < 4; r++) ix[i * 4 + r] = ixn_s[wm * 64 + i * 16 + lq * 4 + r];

    #pragma unroll
    for (int i = 0; i < 4; i++) {
        const int xlocal = wm * 64 + i * 16 + lq * 4;
        #pragma unroll
        for (int j = 0; j < 4; j++) {
            const int ylocal = wn * 64 + j * 16 + lr;
            const float iy = iyn_s[ylocal];
            float c0 = acc[i][j][0] * ix[i * 4 + 0] * iy;
            float c1 = acc[i][j][1] * ix[i * 4 + 1] * iy;
            float c2 = acc[i][j][2] * ix[i * 4 + 2] * iy;
            float c3 = acc[i][j][3] * ix[i * 4 + 3] * iy;
            rmin[i * 4 + 0] = fminf(rmin[i * 4 + 0], 1.f - c0);
            rmin[i * 4 + 1] = fminf(rmin[i * 4 + 1], 1.f - c1);
            rmin[i * 4 + 2] = fminf(rmin[i * 4 + 2], 1.f - c2);
            rmin[i * 4 + 3] = fminf(rmin[i * 4 + 3], 1.f - c3);
            fp16x2 p0 = __builtin_amdgcn_cvt_pkrtz(c0, c1);
            fp16x2 p1 = __builtin_amdgcn_cvt_pkrtz(c2, c3);
            *(float2*)(T + ylocal * 128 + xlocal) =
                make_float2(__builtin_bit_cast(float, p0), __builtin_bit_cast(float, p1));
        }
    }
    #pragma unroll
    for (int m = 1; m < 16; m <<= 1)
        #pragma unroll
        for (int k = 0; k < 16; k++) rmin[k] = fminf(rmin[k], __shfl_xor(rmin[k], m));
    if (lr == 0) {
        #pragma unroll
        for (int i = 0; i < 4; i++)
            #pragma unroll
            for (int r = 0; r < 4; r++)
                atomicMin((int*)&dmin[nb + bx * 128 + wm * 64 + i * 16 + lq * 4 + r],
                          __float_as_int(rmin[i * 4 + r]));
    }
    __syncthreads();

    // coalesced S store: per instr 4 rows × 256 B contiguous segments
    #pragma unroll
    for (int p = 0; p < 8; p++) {
        const int yl = wid * 32 + p * 4 + (lane >> 4);
        const int ch = lane & 15;
        uint4 v = *(const uint4*)(T + yl * 128 + ch * 8);
        *(uint4*)(S + (nb + by * 128 + yl) * (size_t)Nn + bx * 128 + ch * 8) = v;
    }
}

// -------- b1: partial rsum per x over a 512-y strip (2048 blocks) --------------
__global__ __launch_bounds__(256) void b1_rsum(const _Float16* __restrict__ S,
                                               const float* __restrict__ dmin,
                                               float* __restrict__ rsum) {
    __shared__ float red[32 * 65];
    const int t = threadIdx.x;
    const int x0 = blockIdx.x * 64, ys = blockIdx.y, b = blockIdx.z;
    const int chunk = t & 7, yg = t >> 3;
    const int xbase = x0 + chunk * 8;
    const size_t gb = (size_t)b * Nn;

    float invd[8], av[8];
    #pragma unroll
    for (int u = 0; u < 8; u++) {
        float dm = dmin[gb + xbase + u];
        invd[u] = 1.f / (dm + EPS2f);
        av[u] = 1.f - invd[u];
    }
    float s[8];
    #pragma unroll
    for (int u = 0; u < 8; u++) s[u] = 0.f;

    for (int k = 0; k < 16; k++) {
        const int y = ys * 512 + yg + 32 * k;
        half8 hv = *(const half8*)(S + (gb + y) * Nn + xbase);
        #pragma unroll
        for (int u = 0; u < 8; u++)
            s[u] += __expf(fmaf((float)hv[u], invd[u], av[u]));
    }
    #pragma unroll
    for (int u = 0; u < 8; u++) red[yg * 65 + chunk * 8 + u] = s[u];
    __syncthreads();
    if (t < 64) {
        float rs = 0.f;
        #pragma unroll 8
        for (int g = 0; g < 32; g++) rs += red[g * 65 + t];
        atomicAdd(&rsum[gb + x0 + t], rs);
    }
}

// -------- b2: per-y cmax (iv/gg computed inline), per-block CS partial ---------
__global__ __launch_bounds__(256) void b2_cmax(const _Float16* __restrict__ S,
                                               const float* __restrict__ dmin,
                                               const float* __restrict__ rsum,
                                               float* __restrict__ csp) {
    __shared__ float ps[512 * 20];  // 40 KB: (iv,gg) per x, chunk-of-8 stride-20
    __shared__ float red2[16];
    const int t = threadIdx.x, b = blockIdx.y;
    const size_t gb = (size_t)b * Nn;
    for (int i = t; i < Nn; i += 256) {
        float iv = 1.f / (dmin[gb + i] + EPS2f);
        float gg = 1.f - iv - __logf(rsum[gb + i]);
        int c = i >> 3, e = i & 7;
        ps[c * 20 + e * 2] = iv;
        ps[c * 20 + e * 2 + 1] = gg;
    }
    __syncthreads();

    const int lanegrp = t & 15, yloc = t >> 4;
    const int y = blockIdx.x * 16 + yloc;
    const _Float16* Sy = S + (gb + y) * Nn;

    float cm = 0.f;
    for (int k = 0; k < 32; k++) {
        const int chunk = lanegrp + 16 * k;
        half8 hv = *(const half8*)(Sy + chunk * 8);
        const float* pp = &ps[chunk * 20];
        float4 p01 = *(const float4*)(pp);
        float4 p23 = *(const float4*)(pp + 4);
        float4 p45 = *(const float4*)(pp + 8);
        float4 p67 = *(const float4*)(pp + 12);
        float iv[8] = {p01.x, p01.z, p23.x, p23.z, p45.x, p45.z, p67.x, p67.z};
        float gg[8] = {p01.y, p01.w, p23.y, p23.w, p45.y, p45.w, p67.y, p67.w};
        #pragma unroll
        for (int u = 0; u < 8; u++)
            cm = fmaxf(cm, __expf(fmaf((float)hv[u], iv[u], gg[u])));
    }
    #pragma unroll
    for (int m = 1; m < 16; m <<= 1) cm = fmaxf(cm, __shfl_xor(cm, m));
    if (lanegrp == 0) red2[yloc] = cm;
    __syncthreads();
    if (t == 0) {
        float s2 = 0.f;
        #pragma unroll
        for (int i = 0; i < 16; i++) s2 += red2[i];
        csp[b * 256 + blockIdx.x] = s2;
    }
}

// -------- finalize ------------------------------------------------------------
__global__ __launch_bounds__(256) void finalize_kernel(const float* __restrict__ ws,
                                                       float* __restrict__ out) {
    const int t = threadIdx.x;
    float s1 = 0.f, s2 = 0.f, s3 = 0.f;
    if (t < 192) s1 = ws[MSE1P + t];
    for (int i = t; i < 1024; i += 256) { s2 += ws[MSE2P + i]; s3 += ws[CSP + i]; }
    for (int m = 1; m < 64; m <<= 1) {
        s1 += __shfl_xor(s1, m); s2 += __shfl_xor(s2, m); s3 += __shfl_xor(s3, m);
    }
    __shared__ float red[12];
    if ((t & 63) == 0) { int w = t >> 6; red[w * 3] = s1; red[w * 3 + 1] = s2; red[w * 3 + 2] = s3; }
    __syncthreads();
    if (t == 0) {
        s1 = red[0] + red[3] + red[6] + red[9];
        s2 = red[1] + red[4] + red[7] + red[10];
        s3 = red[2] + red[5] + red[8] + red[11];
        float cs = s3 * (1.f / 16384.f);
        out[0] = s1 * (1.f / 786432.f) - logf(cs) + 0.02f * s2 * (1.f / 4194304.f);
    }
}

extern "C" void kernel_launch(void* const* d_in, const int* in_sizes, int n_in,
                              void* d_out, int out_size, void* d_ws, size_t ws_size,
                              hipStream_t stream) {
    const float* outputs = (const float*)d_in[0];
    const float* targets = (const float*)d_in[1];
    const float* ofeat   = (const float*)d_in[2];
    const float* tfeat   = (const float*)d_in[3];
    float* ws  = (float*)d_ws;
    float* out = (float*)d_out;

    unsigned short* Xc = (unsigned short*)(ws + XCO);
    unsigned short* Yc = (unsigned short*)(ws + YCO);
    _Float16* S = (_Float16*)(ws + SOFF);

    prep1<<<1344, 256, 0, stream>>>((const float4*)outputs, (const float4*)targets,
                                    (const float4*)ofeat, (const float4*)tfeat, ws);
    center_fused<<<dim3(Nn / 64, Bn, 2), 256, 0, stream>>>(ofeat, tfeat, ws);
    gemm_store<<<dim3(Nn / 128, Nn / 128, Bn), 256, 0, stream>>>(Xc, Yc, ws + IXN, ws + IYN,
                                                                 ws + DMIN, S);
    b1_rsum<<<dim3(64, 8, Bn), 256, 0, stream>>>(S, ws + DMIN, ws + RSUM);
    b2_cmax<<<dim3(Nn / 16, Bn), 256, 0, stream>>>(S, ws + DMIN, ws + RSUM, ws + CSP);
    finalize_kernel<<<1, 256, 0, stream>>>(ws, out);
}

// Round 5
// 237.866 us; speedup vs baseline: 1.2011x; 1.2011x over previous
//
#include <hip/hip_runtime.h>
#include <hip/hip_bf16.h>
#include <cstdint>

#define EPS2f 1e-5f

typedef __bf16 bf16x8 __attribute__((ext_vector_type(8)));
typedef float floatx4 __attribute__((ext_vector_type(4)));
typedef _Float16 half8 __attribute__((ext_vector_type(8)));
typedef __fp16 fp16x2 __attribute__((ext_vector_type(2)));

static constexpr int Bn = 4, Cn = 256, Nn = 4096;

// workspace layout (float offsets) — total ~151.28 MB (R3 proved ws >= 151.59 MB)
static constexpr size_t MSE1P = 0;        // 192
static constexpr size_t MSE2P = 256;      // 1024
static constexpr size_t CSP   = 1536;     // 1024
static constexpr size_t MEANX = 2560;     // 1024
static constexpr size_t MEANY = 3584;     // 1024
static constexpr size_t IXN   = 4608;     // 16384
static constexpr size_t IYN   = 20992;    // 16384
static constexpr size_t DMIN  = 37376;    // 16384
static constexpr size_t RSUM  = 53760;    // 16384
static constexpr size_t XCO   = 70144;    // bf16[4*4096*256]
static constexpr size_t YCO   = 70144 + 2097152;
static constexpr size_t SOFF  = 70144 + 2 * 2097152;  // fp16[4*4096*4096]

__device__ __forceinline__ unsigned short f2bf(float f) {
    unsigned u = __float_as_uint(f);
    u += 0x7fffu + ((u >> 16) & 1u);
    return (unsigned short)(u >> 16);
}

// -------- prep1: channel means + both MSE partials + dmin/rsum init --------
__global__ __launch_bounds__(256) void prep1(const float4* __restrict__ outs,
                                             const float4* __restrict__ tgts,
                                             const float4* __restrict__ of4,
                                             const float4* __restrict__ tf4,
                                             float* __restrict__ ws) {
    const int bid = blockIdx.x, t = threadIdx.x;
    __shared__ float red[12];
    if (bid < 1024) {
        const int c = bid & 255, b = bid >> 8;
        const float4* po = of4 + ((size_t)b * Cn + c) * (Nn / 4);
        const float4* pt = tf4 + ((size_t)b * Cn + c) * (Nn / 4);
        float so = 0.f, st = 0.f, sq = 0.f;
        for (int i = t; i < 1024; i += 256) {
            float4 o = po[i], q = pt[i];
            so += o.x + o.y + o.z + o.w;
            st += q.x + q.y + q.z + q.w;
            float dx = o.x - q.x, dy = o.y - q.y, dz = o.z - q.z, dw = o.w - q.w;
            sq += dx * dx + dy * dy + dz * dz + dw * dw;
        }
        for (int m = 1; m < 64; m <<= 1) {
            so += __shfl_xor(so, m); st += __shfl_xor(st, m); sq += __shfl_xor(sq, m);
        }
        if ((t & 63) == 0) { int w = t >> 6; red[w * 3] = so; red[w * 3 + 1] = st; red[w * 3 + 2] = sq; }
        __syncthreads();
        if (t == 0) {
            so = red[0] + red[3] + red[6] + red[9];
            st = red[1] + red[4] + red[7] + red[10];
            sq = red[2] + red[5] + red[8] + red[11];
            ws[MEANX + b * Cn + c] = so * (1.f / 4096.f);
            ws[MEANY + b * Cn + c] = st * (1.f / 4096.f);
            ws[MSE2P + bid] = sq;
        }
    } else if (bid < 1216) {
        const int base = bid - 1024;
        float sq = 0.f;
        for (int i = base * 256 + t; i < 196608; i += 192 * 256) {
            float4 a = outs[i], b4 = tgts[i];
            float dx = a.x - b4.x, dy = a.y - b4.y, dz = a.z - b4.z, dw = a.w - b4.w;
            sq += dx * dx + dy * dy + dz * dz + dw * dw;
        }
        for (int m = 1; m < 64; m <<= 1) sq += __shfl_xor(sq, m);
        if ((t & 63) == 0) red[t >> 6] = sq;
        __syncthreads();
        if (t == 0) ws[MSE1P + base] = red[0] + red[1] + red[2] + red[3];
    } else {
        const int i = (bid - 1216) * 256 + t;  // 0..32767 → dmin then rsum
        ws[DMIN + i] = (i < 16384) ? __builtin_inff() : 0.f;
    }
}

// -------- center: per-channel centering, bf16 [b][n][c] transpose, inv norms ----
__global__ __launch_bounds__(256) void center_fused(const float* __restrict__ ofeat,
                                                    const float* __restrict__ tfeat,
                                                    float* __restrict__ ws) {
    const int b = blockIdx.y, nb = blockIdx.x, z = blockIdx.z;
    const float* feat = z ? tfeat : ofeat;
    const float* mean = ws + (z ? MEANY : MEANX);
    unsigned short* outb = (unsigned short*)(ws + (z ? YCO : XCO));
    float* inv = ws + (z ? IYN : IXN);
    __shared__ float mean_s[256];
    __shared__ float sq_s[256];
    const int t = threadIdx.x;
    mean_s[t] = mean[b * Cn + t];
    __syncthreads();
    const int pos = t & 63, cg = t >> 6;
    const int n = nb * 64 + pos;
    const float* fb = feat + (size_t)b * Cn * Nn;
    unsigned short* ob = outb + ((size_t)b * Nn + n) * Cn;
    float ss = 0.f;
    for (int c0 = cg * 64; c0 < cg * 64 + 64; c0 += 8) {
        unsigned short tmp[8];
        #pragma unroll
        for (int u = 0; u < 8; ++u) {
            float v = fb[(size_t)(c0 + u) * Nn + n] - mean_s[c0 + u];
            ss += v * v;
            tmp[u] = f2bf(v);
        }
        uint4 pk;
        pk.x = (unsigned)tmp[0] | ((unsigned)tmp[1] << 16);
        pk.y = (unsigned)tmp[2] | ((unsigned)tmp[3] << 16);
        pk.z = (unsigned)tmp[4] | ((unsigned)tmp[5] << 16);
        pk.w = (unsigned)tmp[6] | ((unsigned)tmp[7] << 16);
        *(uint4*)(ob + c0) = pk;
    }
    sq_s[t] = ss;
    __syncthreads();
    if (t < 64) {
        float s = sq_s[t] + sq_s[t + 64] + sq_s[t + 128] + sq_s[t + 192];
        inv[(size_t)b * Nn + nb * 64 + t] = 1.f / sqrtf(s);
    }
}

// -------- GEMM: dbuf LDS staging (conflict-free layout) + swizzled-T store -----
// smem (32 KB) = 2 staging buffers [As|Bs], each As/Bs = [kchunk(4)][row(128)][8]
// shorts; after the K-loop it is reused as the 128x128 fp16 transpose tile T.
__global__ __launch_bounds__(256) void gemm_store(const unsigned short* __restrict__ Xc,
                                                  const unsigned short* __restrict__ Yc,
                                                  const float* __restrict__ ixn,
                                                  const float* __restrict__ iyn,
                                                  float* __restrict__ dmin,
                                                  _Float16* __restrict__ S) {
    __shared__ __align__(16) unsigned short smem[16384];  // 32 KB
    __shared__ float ixn_s[128], iyn_s[128];

    const int t = threadIdx.x;
    const int bx = blockIdx.x, by = blockIdx.y, b = blockIdx.z;
    const size_t nb = (size_t)b * Nn;

    if (t < 128) ixn_s[t] = ixn[nb + bx * 128 + t];
    else iyn_s[t - 128] = iyn[nb + by * 128 + (t - 128)];

    const int wid = t >> 6, lane = t & 63;
    const int wm = wid >> 1, wn = wid & 1;
    const int lr = lane & 15, lq = lane >> 4;
    const int srow = t >> 2, sq = t & 3;

    const unsigned short* Ag = Xc + (nb + bx * 128) * Cn;
    const unsigned short* Bg = Yc + (nb + by * 128) * Cn;
    // thread stages rows {srow, srow+64}, k-slice sq*8.. within current 32-chunk
    const unsigned short* Ga0 = Ag + (size_t)srow * Cn + sq * 8;
    const unsigned short* Ga1 = Ag + (size_t)(srow + 64) * Cn + sq * 8;
    const unsigned short* Gb0 = Bg + (size_t)srow * Cn + sq * 8;
    const unsigned short* Gb1 = Bg + (size_t)(srow + 64) * Cn + sq * 8;
    // LDS staging dest: buf*8192 + (A=0|B=4096) + (kchunk*128 + row)*8
    const int wA0 = (sq * 128 + srow) * 8;
    const int wA1 = (sq * 128 + srow + 64) * 8;

    floatx4 acc[4][4];
    #pragma unroll
    for (int i = 0; i < 4; i++)
        #pragma unroll
        for (int j = 0; j < 4; j++) acc[i][j] = (floatx4){0.f, 0.f, 0.f, 0.f};

    // preload k-chunk 0 into buf 0
    {
        uint4 a0 = *(const uint4*)Ga0, a1 = *(const uint4*)Ga1;
        uint4 b0 = *(const uint4*)Gb0, b1 = *(const uint4*)Gb1;
        *(uint4*)(smem + wA0) = a0;
        *(uint4*)(smem + wA1) = a1;
        *(uint4*)(smem + 4096 + wA0) = b0;
        *(uint4*)(smem + 4096 + wA1) = b1;
    }
    __syncthreads();

    #pragma unroll
    for (int ks = 0; ks < 8; ks++) {
        const int cur = (ks & 1) * 8192, nxt = 8192 - cur;
        uint4 a0, a1, b0, b1;
        if (ks < 7) {
            a0 = *(const uint4*)(Ga0 + (ks + 1) * 32);
            a1 = *(const uint4*)(Ga1 + (ks + 1) * 32);
            b0 = *(const uint4*)(Gb0 + (ks + 1) * 32);
            b1 = *(const uint4*)(Gb1 + (ks + 1) * 32);
        }
        bf16x8 af[4], bv[4];
        #pragma unroll
        for (int i = 0; i < 4; i++)
            af[i] = *(const bf16x8*)(smem + cur + (lq * 128 + wm * 64 + i * 16 + lr) * 8);
        #pragma unroll
        for (int j = 0; j < 4; j++)
            bv[j] = *(const bf16x8*)(smem + cur + 4096 + (lq * 128 + wn * 64 + j * 16 + lr) * 8);
        #pragma unroll
        for (int i = 0; i < 4; i++)
            #pragma unroll
            for (int j = 0; j < 4; j++)
                acc[i][j] = __builtin_amdgcn_mfma_f32_16x16x32_bf16(af[i], bv[j], acc[i][j], 0, 0, 0);
        if (ks < 7) {
            *(uint4*)(smem + nxt + wA0) = a0;
            *(uint4*)(smem + nxt + wA1) = a1;
            *(uint4*)(smem + nxt + 4096 + wA0) = b0;
            *(uint4*)(smem + nxt + 4096 + wA1) = b1;
            __syncthreads();
        }
    }

    // epilogue 1: dmin (registers + shfl only)
    float ix[16];
    #pragma unroll
    for (int i = 0; i < 4; i++)
        #pragma unroll
        for (int r = 0; r < 4; r++) ix[i * 4 + r] = ixn_s[wm * 64 + i * 16 + lq * 4 + r];
    float rmin[16];
    #pragma unroll
    for (int k = 0; k < 16; k++) rmin[k] = __builtin_inff();
    #pragma unroll
    for (int i = 0; i < 4; i++)
        #pragma unroll
        for (int j = 0; j < 4; j++) {
            const float iy = iyn_s[wn * 64 + j * 16 + lr];
            #pragma unroll
            for (int r = 0; r < 4; r++)
                rmin[i * 4 + r] = fminf(rmin[i * 4 + r], 1.f - acc[i][j][r] * ix[i * 4 + r] * iy);
        }
    #pragma unroll
    for (int m = 1; m < 16; m <<= 1)
        #pragma unroll
        for (int k = 0; k < 16; k++) rmin[k] = fminf(rmin[k], __shfl_xor(rmin[k], m));
    if (lr == 0) {
        #pragma unroll
        for (int i = 0; i < 4; i++)
            #pragma unroll
            for (int r = 0; r < 4; r++)
                atomicMin((int*)&dmin[nb + bx * 128 + wm * 64 + i * 16 + lq * 4 + r],
                          __float_as_int(rmin[i * 4 + r]));
    }
    __syncthreads();  // all waves done with staging reads; smem reused as T

    // epilogue 2: fp16 transpose tile with XOR swizzle (x ^= (y&15)*8)
    #pragma unroll
    for (int i = 0; i < 4; i++) {
        const int xlocal = wm * 64 + i * 16 + lq * 4;
        #pragma unroll
        for (int j = 0; j < 4; j++) {
            const int ylocal = wn * 64 + j * 16 + lr;
            const float iy = iyn_s[ylocal];
            float c0 = acc[i][j][0] * ix[i * 4 + 0] * iy;
            float c1 = acc[i][j][1] * ix[i * 4 + 1] * iy;
            float c2 = acc[i][j][2] * ix[i * 4 + 2] * iy;
            float c3 = acc[i][j][3] * ix[i * 4 + 3] * iy;
            fp16x2 p0 = __builtin_amdgcn_cvt_pkrtz(c0, c1);
            fp16x2 p1 = __builtin_amdgcn_cvt_pkrtz(c2, c3);
            *(float2*)(smem + ylocal * 128 + (xlocal ^ ((ylocal & 15) * 8))) =
                make_float2(__builtin_bit_cast(float, p0), __builtin_bit_cast(float, p1));
        }
    }
    __syncthreads();

    // coalesced store: 4 rows x 256 B contiguous per instruction
    #pragma unroll
    for (int p = 0; p < 8; p++) {
        const int yl = wid * 32 + p * 4 + (lane >> 4);
        const int ch = lane & 15;
        uint4 v = *(const uint4*)(smem + yl * 128 + ((ch * 8) ^ ((yl & 15) * 8)));
        *(uint4*)(S + (nb + by * 128 + yl) * (size_t)Nn + bx * 128 + ch * 8) = v;
    }
}

// -------- b1: partial rsum per x over a 512-y strip (2048 blocks) --------------
__global__ __launch_bounds__(256) void b1_rsum(const _Float16* __restrict__ S,
                                               const float* __restrict__ dmin,
                                               float* __restrict__ rsum) {
    __shared__ float red[32 * 65];
    const int t = threadIdx.x;
    const int x0 = blockIdx.x * 64, ys = blockIdx.y, b = blockIdx.z;
    const int chunk = t & 7, yg = t >> 3;
    const int xbase = x0 + chunk * 8;
    const size_t gb = (size_t)b * Nn;

    float invd[8], av[8];
    #pragma unroll
    for (int u = 0; u < 8; u++) {
        float dm = dmin[gb + xbase + u];
        invd[u] = 1.f / (dm + EPS2f);
        av[u] = 1.f - invd[u];
    }
    float s[8];
    #pragma unroll
    for (int u = 0; u < 8; u++) s[u] = 0.f;

    for (int k = 0; k < 16; k++) {
        const int y = ys * 512 + yg + 32 * k;
        half8 hv = *(const half8*)(S + (gb + y) * Nn + xbase);
        #pragma unroll
        for (int u = 0; u < 8; u++)
            s[u] += __expf(fmaf((float)hv[u], invd[u], av[u]));
    }
    #pragma unroll
    for (int u = 0; u < 8; u++) red[yg * 65 + chunk * 8 + u] = s[u];
    __syncthreads();
    if (t < 64) {
        float rs = 0.f;
        #pragma unroll 8
        for (int g = 0; g < 32; g++) rs += red[g * 65 + t];
        atomicAdd(&rsum[gb + x0 + t], rs);
    }
}

// -------- b2: per-y cmax (iv/gg inline), per-block CS partial ------------------
__global__ __launch_bounds__(256) void b2_cmax(const _Float16* __restrict__ S,
                                               const float* __restrict__ dmin,
                                               const float* __restrict__ rsum,
                                               float* __restrict__ csp) {
    __shared__ float ps[512 * 20];
    __shared__ float red2[16];
    const int t = threadIdx.x, b = blockIdx.y;
    const size_t gb = (size_t)b * Nn;
    for (int i = t; i < Nn; i += 256) {
        float iv = 1.f / (dmin[gb + i] + EPS2f);
        float gg = 1.f - iv - __logf(rsum[gb + i]);
        int c = i >> 3, e = i & 7;
        ps[c * 20 + e * 2] = iv;
        ps[c * 20 + e * 2 + 1] = gg;
    }
    __syncthreads();

    const int lanegrp = t & 15, yloc = t >> 4;
    const int y = blockIdx.x * 16 + yloc;
    const _Float16* Sy = S + (gb + y) * Nn;

    float cm = 0.f;
    for (int k = 0; k < 32; k++) {
        const int chunk = lanegrp + 16 * k;
        half8 hv = *(const half8*)(Sy + chunk * 8);
        const float* pp = &ps[chunk * 20];
        float4 p01 = *(const float4*)(pp);
        float4 p23 = *(const float4*)(pp + 4);
        float4 p45 = *(const float4*)(pp + 8);
        float4 p67 = *(const float4*)(pp + 12);
        float iv[8] = {p01.x, p01.z, p23.x, p23.z, p45.x, p45.z, p67.x, p67.z};
        float gg[8] = {p01.y, p01.w, p23.y, p23.w, p45.y, p45.w, p67.y, p67.w};
        #pragma unroll
        for (int u = 0; u < 8; u++)
            cm = fmaxf(cm, __expf(fmaf((float)hv[u], iv[u], gg[u])));
    }
    #pragma unroll
    for (int m = 1; m < 16; m <<= 1) cm = fmaxf(cm, __shfl_xor(cm, m));
    if (lanegrp == 0) red2[yloc] = cm;
    __syncthreads();
    if (t == 0) {
        float s2 = 0.f;
        #pragma unroll
        for (int i = 0; i < 16; i++) s2 += red2[i];
        csp[b * 256 + blockIdx.x] = s2;
    }
}

// -------- finalize ------------------------------------------------------------
__global__ __launch_bounds__(256) void finalize_kernel(const float* __restrict__ ws,
                                                       float* __restrict__ out) {
    const int t = threadIdx.x;
    float s1 = 0.f, s2 = 0.f, s3 = 0.f;
    if (t < 192) s1 = ws[MSE1P + t];
    for (int i = t; i < 1024; i += 256) { s2 += ws[MSE2P + i]; s3 += ws[CSP + i]; }
    for (int m = 1; m < 64; m <<= 1) {
        s1 += __shfl_xor(s1, m); s2 += __shfl_xor(s2, m); s3 += __shfl_xor(s3, m);
    }
    __shared__ float red[12];
    if ((t & 63) == 0) { int w = t >> 6; red[w * 3] = s1; red[w * 3 + 1] = s2; red[w * 3 + 2] = s3; }
    __syncthreads();
    if (t == 0) {
        s1 = red[0] + red[3] + red[6] + red[9];
        s2 = red[1] + red[4] + red[7] + red[10];
        s3 = red[2] + red[5] + red[8] + red[11];
        float cs = s3 * (1.f / 16384.f);
        out[0] = s1 * (1.f / 786432.f) - logf(cs) + 0.02f * s2 * (1.f / 4194304.f);
    }
}

extern "C" void kernel_launch(void* const* d_in, const int* in_sizes, int n_in,
                              void* d_out, int out_size, void* d_ws, size_t ws_size,
                              hipStream_t stream) {
    const float* outputs = (const float*)d_in[0];
    const float* targets = (const float*)d_in[1];
    const float* ofeat   = (const float*)d_in[2];
    const float* tfeat   = (const float*)d_in[3];
    float* ws  = (float*)d_ws;
    float* out = (float*)d_out;

    unsigned short* Xc = (unsigned short*)(ws + XCO);
    unsigned short* Yc = (unsigned short*)(ws + YCO);
    _Float16* S = (_Float16*)(ws + SOFF);

    prep1<<<1344, 256, 0, stream>>>((const float4*)outputs, (const float4*)targets,
                                    (const float4*)ofeat, (const float4*)tfeat, ws);
    center_fused<<<dim3(Nn / 64, Bn, 2), 256, 0, stream>>>(ofeat, tfeat, ws);
    gemm_store<<<dim3(Nn / 128, Nn / 128, Bn), 256, 0, stream>>>(Xc, Yc, ws + IXN, ws + IYN,
                                                                 ws + DMIN, S);
    b1_rsum<<<dim3(64, 8, Bn), 256, 0, stream>>>(S, ws + DMIN, ws + RSUM);
    b2_cmax<<<dim3(Nn / 16, Bn), 256, 0, stream>>>(S, ws + DMIN, ws + RSUM, ws + CSP);
    finalize_kernel<<<1, 256, 0, stream>>>(ws, out);
}